// Round 1
// baseline (27.080 us; speedup 1.0000x reference)
//
#include <hip/hip_runtime.h>
#include <math.h>

// PointNet semantic-seg loss:
//   logp = log_softmax(pred, -1); logp_t = logp[.., target]
//   ce   = -mean(logp_t)
//   loss = mean(1 - exp(logp_t)) * ce           (GAMMA = 1)
//   dice = 1 - 2*(sum(pred_choice==target) + 1) / (2*B*N + 1)
//   out  = loss + dice
//
// C = 50 classes (hard-coded; row stride 200 B -> float2-aligned loads).

#define NCLS 50
#define BLK 256

__global__ __launch_bounds__(BLK) void pnloss_main(
    const float* __restrict__ pred,
    const int* __restrict__ targets,
    const int* __restrict__ pchoice,
    float* __restrict__ partials,   // [3][nblocks]
    int rows, int nblocks)
{
    const int row = blockIdx.x * BLK + threadIdx.x;

    float logpt = 0.f, pn = 0.f, match = 0.f;

    if (row < rows) {
        const float2* rp = reinterpret_cast<const float2*>(pred + (size_t)row * NCLS);
        float2 v[NCLS / 2];
        #pragma unroll
        for (int j = 0; j < NCLS / 2; ++j) v[j] = rp[j];

        const int t = targets[row];

        // max + capture x[target] with static indexing only
        float m = v[0].x;
        float xt = 0.f;
        #pragma unroll
        for (int j = 0; j < NCLS / 2; ++j) {
            m = fmaxf(m, fmaxf(v[j].x, v[j].y));
            xt = (t == 2 * j)     ? v[j].x : xt;
            xt = (t == 2 * j + 1) ? v[j].y : xt;
        }

        float s = 0.f;
        #pragma unroll
        for (int j = 0; j < NCLS / 2; ++j)
            s += __expf(v[j].x - m) + __expf(v[j].y - m);

        logpt = xt - m - __logf(s);
        pn    = __expf(logpt);
        match = (pchoice[row] == t) ? 1.f : 0.f;
    }

    // wave reduce (64 lanes)
    #pragma unroll
    for (int off = 32; off > 0; off >>= 1) {
        logpt += __shfl_down(logpt, off);
        pn    += __shfl_down(pn, off);
        match += __shfl_down(match, off);
    }

    __shared__ float sm[3][BLK / 64];
    const int wid  = threadIdx.x >> 6;
    const int lane = threadIdx.x & 63;
    if (lane == 0) { sm[0][wid] = logpt; sm[1][wid] = pn; sm[2][wid] = match; }
    __syncthreads();

    if (threadIdx.x == 0) {
        float a = 0.f, b = 0.f, c = 0.f;
        #pragma unroll
        for (int w = 0; w < BLK / 64; ++w) { a += sm[0][w]; b += sm[1][w]; c += sm[2][w]; }
        partials[blockIdx.x]               = a;
        partials[blockIdx.x + nblocks]     = b;
        partials[blockIdx.x + 2 * nblocks] = c;
    }
}

__global__ __launch_bounds__(BLK) void pnloss_final(
    const float* __restrict__ partials,
    int nblocks, float inv_rows, float two_rows,
    float* __restrict__ out)
{
    float a = 0.f, b = 0.f, c = 0.f;
    for (int i = threadIdx.x; i < nblocks; i += BLK) {
        a += partials[i];
        b += partials[i + nblocks];
        c += partials[i + 2 * nblocks];
    }

    #pragma unroll
    for (int off = 32; off > 0; off >>= 1) {
        a += __shfl_down(a, off);
        b += __shfl_down(b, off);
        c += __shfl_down(c, off);
    }

    __shared__ float sm[3][BLK / 64];
    const int wid  = threadIdx.x >> 6;
    const int lane = threadIdx.x & 63;
    if (lane == 0) { sm[0][wid] = a; sm[1][wid] = b; sm[2][wid] = c; }
    __syncthreads();

    if (threadIdx.x == 0) {
        float sa = 0.f, sb = 0.f, sc = 0.f;
        #pragma unroll
        for (int w = 0; w < BLK / 64; ++w) { sa += sm[0][w]; sb += sm[1][w]; sc += sm[2][w]; }
        const float ce    = -sa * inv_rows;              // cross-entropy mean
        const float focal = 1.f - sb * inv_rows;         // mean(1 - pn), GAMMA=1
        const float loss  = focal * ce;
        const float dice  = 1.f - 2.f * (sc + 1.f) / (two_rows + 1.f);  // DICE_EPS=1
        out[0] = loss + dice;
    }
}

extern "C" void kernel_launch(void* const* d_in, const int* in_sizes, int n_in,
                              void* d_out, int out_size, void* d_ws, size_t ws_size,
                              hipStream_t stream) {
    const float* pred    = (const float*)d_in[0];
    const int*   targets = (const int*)d_in[1];
    const int*   pchoice = (const int*)d_in[2];
    float*       out     = (float*)d_out;
    float*       partials = (float*)d_ws;

    const int rows    = in_sizes[1];                 // B*N = 524288
    const int nblocks = (rows + BLK - 1) / BLK;      // 2048

    pnloss_main<<<nblocks, BLK, 0, stream>>>(pred, targets, pchoice, partials, rows, nblocks);
    pnloss_final<<<1, BLK, 0, stream>>>(partials, nblocks,
                                        1.0f / (float)rows, 2.0f * (float)rows, out);
}

// Round 2
// 26.386 us; speedup vs baseline: 1.0263x; 1.0263x over previous
//
#include <hip/hip_runtime.h>
#include <math.h>

// PointNet semantic-seg loss:
//   logp = log_softmax(pred, -1); logp_t = logp[.., target]
//   ce   = -mean(logp_t)
//   loss = mean(1 - exp(logp_t)) * ce           (GAMMA = 1)
//   dice = 1 - 2*(sum(pred_choice==target) + 1) / (2*B*N + 1)
//   out  = loss + dice
//
// C = 50 classes. Rows are 200 B. A block stages 256 rows (51.2 KB, float4-
// aligned) into LDS with coalesced float4 loads, then each thread computes
// its row's log-softmax-at-target from LDS. This replaces the R0 pattern
// (64 distinct cache lines per wave load -> TA-transaction-bound).

#define NCLS 50
#define BLK 256
#define RPB 256                      // rows per block
#define NF4 (RPB * NCLS / 4)         // 3200 float4 per block
#define FULLK (NF4 / BLK)            // 12 full rounds; tail = 128

__global__ __launch_bounds__(BLK) void pnloss_main(
    const float* __restrict__ pred,
    const int* __restrict__ targets,
    const int* __restrict__ pchoice,
    float* __restrict__ partials,    // [3][nblocks]
    int rows, int nblocks)
{
    __shared__ float sdata[RPB * NCLS];   // 51200 B

    const int tid = threadIdx.x;
    const int rowbase = blockIdx.x * RPB;

    // ---- stage 256 rows into LDS, fully coalesced float4 ----
    if (rowbase + RPB <= rows) {
        const float4* gp = reinterpret_cast<const float4*>(pred + (size_t)rowbase * NCLS);
        float4* sp = reinterpret_cast<float4*>(sdata);

        float4 tmp[FULLK];
        #pragma unroll
        for (int k = 0; k < FULLK; ++k) tmp[k] = gp[tid + k * BLK];
        float4 tail;
        const bool has_tail = tid < (NF4 - FULLK * BLK);
        if (has_tail) tail = gp[tid + FULLK * BLK];

        #pragma unroll
        for (int k = 0; k < FULLK; ++k) sp[tid + k * BLK] = tmp[k];
        if (has_tail) sp[tid + FULLK * BLK] = tail;
    } else {
        // ragged last block: guarded scalar staging
        const size_t fbase = (size_t)rowbase * NCLS;
        const size_t ftotal = (size_t)rows * NCLS;
        for (int i = tid; i < RPB * NCLS; i += BLK) {
            sdata[i] = (fbase + i < ftotal) ? pred[fbase + i] : 0.f;
        }
    }
    __syncthreads();

    // ---- per-row log-softmax at target ----
    const int row = rowbase + tid;
    float logpt = 0.f, pn = 0.f, match = 0.f;

    if (row < rows) {
        const float2* rp = reinterpret_cast<const float2*>(sdata + tid * NCLS);
        float2 v[NCLS / 2];
        #pragma unroll
        for (int j = 0; j < NCLS / 2; ++j) v[j] = rp[j];

        const int t = targets[row];
        const float xt = sdata[tid * NCLS + t];   // one dynamic LDS read

        float m = v[0].x;
        #pragma unroll
        for (int j = 0; j < NCLS / 2; ++j) m = fmaxf(m, fmaxf(v[j].x, v[j].y));

        float s = 0.f;
        #pragma unroll
        for (int j = 0; j < NCLS / 2; ++j)
            s += __expf(v[j].x - m) + __expf(v[j].y - m);

        logpt = xt - m - __logf(s);
        pn    = __expf(logpt);
        match = (pchoice[row] == t) ? 1.f : 0.f;
    }

    // ---- wave + block reduce ----
    #pragma unroll
    for (int off = 32; off > 0; off >>= 1) {
        logpt += __shfl_down(logpt, off);
        pn    += __shfl_down(pn, off);
        match += __shfl_down(match, off);
    }

    __shared__ float sm[3][BLK / 64];
    const int wid  = tid >> 6;
    const int lane = tid & 63;
    if (lane == 0) { sm[0][wid] = logpt; sm[1][wid] = pn; sm[2][wid] = match; }
    __syncthreads();

    if (tid == 0) {
        float a = 0.f, b = 0.f, c = 0.f;
        #pragma unroll
        for (int w = 0; w < BLK / 64; ++w) { a += sm[0][w]; b += sm[1][w]; c += sm[2][w]; }
        partials[blockIdx.x]               = a;
        partials[blockIdx.x + nblocks]     = b;
        partials[blockIdx.x + 2 * nblocks] = c;
    }
}

__global__ __launch_bounds__(BLK) void pnloss_final(
    const float* __restrict__ partials,
    int nblocks, float inv_rows, float two_rows,
    float* __restrict__ out)
{
    float a = 0.f, b = 0.f, c = 0.f;
    for (int i = threadIdx.x; i < nblocks; i += BLK) {
        a += partials[i];
        b += partials[i + nblocks];
        c += partials[i + 2 * nblocks];
    }

    #pragma unroll
    for (int off = 32; off > 0; off >>= 1) {
        a += __shfl_down(a, off);
        b += __shfl_down(b, off);
        c += __shfl_down(c, off);
    }

    __shared__ float sm[3][BLK / 64];
    const int wid  = threadIdx.x >> 6;
    const int lane = threadIdx.x & 63;
    if (lane == 0) { sm[0][wid] = a; sm[1][wid] = b; sm[2][wid] = c; }
    __syncthreads();

    if (threadIdx.x == 0) {
        float sa = 0.f, sb = 0.f, sc = 0.f;
        #pragma unroll
        for (int w = 0; w < BLK / 64; ++w) { sa += sm[0][w]; sb += sm[1][w]; sc += sm[2][w]; }
        const float ce    = -sa * inv_rows;                     // CE mean
        const float focal = 1.f - sb * inv_rows;                // mean(1 - pn)
        const float loss  = focal * ce;
        const float dice  = 1.f - 2.f * (sc + 1.f) / (two_rows + 1.f);
        out[0] = loss + dice;
    }
}

extern "C" void kernel_launch(void* const* d_in, const int* in_sizes, int n_in,
                              void* d_out, int out_size, void* d_ws, size_t ws_size,
                              hipStream_t stream) {
    const float* pred     = (const float*)d_in[0];
    const int*   targets  = (const int*)d_in[1];
    const int*   pchoice  = (const int*)d_in[2];
    float*       out      = (float*)d_out;
    float*       partials = (float*)d_ws;

    const int rows    = in_sizes[1];                 // B*N = 524288
    const int nblocks = (rows + RPB - 1) / RPB;      // 2048

    pnloss_main<<<nblocks, BLK, 0, stream>>>(pred, targets, pchoice, partials, rows, nblocks);
    pnloss_final<<<1, BLK, 0, stream>>>(partials, nblocks,
                                        1.0f / (float)rows, 2.0f * (float)rows, out);
}